// Round 8
// baseline (61.711 us; speedup 1.0000x reference)
//
#include <hip/hip_runtime.h>
#include <math.h>

// Dims: B=4, C=8, H=W=256
#define B_DIM 4
#define C_DIM 8
#define H_DIM 256
#define W_DIM 256
#define HW 65536
#define NPIX 262144

// ws layout (no zero-init required; every slot written every call):
// [0,     4096)   float pce[1024]
// [4096,  8192)   float pinter[1024]
// [8192, 16384)   int2  pcnt[1024]
// [16384,20480)   float pbound[1024]
// [20480,20484)   uint  done            (zeroed by k_row block 0 each call)
// [24576,40960)   uchar rowflagP[64*256]
// [65536,+1MB)    float lse[NPIX]
// [2MB,  +8MB)    uint  d1t[32][16][256][16]  tiled: [bc][xt][y][word]; word = d1_pol0 | d1_pol1<<16

__device__ __forceinline__ float wave_reduce_f(float v) {
#pragma unroll
    for (int off = 32; off; off >>= 1) v += __shfl_xor(v, off, 64);
    return v;
}
__device__ __forceinline__ int wave_reduce_max_i(int v) {
#pragma unroll
    for (int off = 32; off; off >>= 1) v = max(v, __shfl_xor(v, off, 64));
    return v;
}

// ------------- Kernel 1: fused softmax stats + horizontal EDT for one (b,y) row -------------
__global__ void __launch_bounds__(256) k_row(
    const float* __restrict__ x, const int* __restrict__ tgt,
    float* __restrict__ lse_out, float* __restrict__ pce, float* __restrict__ pinter,
    int2* __restrict__ pcnt, unsigned char* __restrict__ rowflagP,
    unsigned int* __restrict__ d1t, unsigned int* __restrict__ done) {
    int bi = blockIdx.x;                 // [0,1024): b*256 + y
    int b = bi >> 8, y = bi & 255;
    int i = threadIdx.x;                 // column
    int lane = i & 63, wid = i >> 6;
    size_t rowbase = (size_t)b * HW + (size_t)y * W_DIM;

    if (bi == 0 && i == 0) *done = 0u;   // stream-ordered before kernel 2

    // ---- softmax / CE / Dice stats ----
    const float* xb = x + (size_t)b * C_DIM * HW + (size_t)y * W_DIM + i;
    float v[C_DIM];
    float m = -1e30f;
#pragma unroll
    for (int c = 0; c < C_DIM; ++c) { v[c] = xb[(size_t)c * HW]; m = fmaxf(m, v[c]); }
    float s = 0.f;
#pragma unroll
    for (int c = 0; c < C_DIM; ++c) s += __expf(v[c] - m);
    float lse = m + __logf(s);
    lse_out[rowbase + i] = lse;

    int t = tgt[rowbase + i];
    bool valid_d = (t >= 0);
    bool valid_b = valid_d && (t < C_DIM);
    int tc = valid_b ? t : 0;
    float vt = v[0];
#pragma unroll
    for (int c = 1; c < C_DIM; ++c) vt = (tc == c) ? v[c] : vt;

    float ce = lse - vt;
    float inter = valid_b ? __expf(vt - m) * (1.0f / s) : 0.f;

    __shared__ float ws_ce[4], ws_in[4];
    __shared__ int ws_cd[4], ws_cb[4];
    float r_ce = wave_reduce_f(ce);
    float r_in = wave_reduce_f(inter);
    unsigned long long md = __ballot(valid_d);
    unsigned long long mbv = __ballot(valid_b);
    if (lane == 0) {
        ws_ce[wid] = r_ce; ws_in[wid] = r_in;
        ws_cd[wid] = __popcll(md); ws_cb[wid] = __popcll(mbv);
    }

    // ---- row EDT via ballot masks ----
    __shared__ unsigned long long wmask[C_DIM][4];
#pragma unroll
    for (int c = 0; c < C_DIM; ++c) {
        unsigned long long mc = __ballot(valid_b && (t == c));
        if (lane == 0) wmask[c][wid] = mc;
    }
    __syncthreads();

    if (i == 0) {
        pce[bi] = (ws_ce[0] + ws_ce[1]) + (ws_ce[2] + ws_ce[3]);
        pinter[bi] = (ws_in[0] + ws_in[1]) + (ws_in[2] + ws_in[3]);
        pcnt[bi] = make_int2((ws_cd[0] + ws_cd[1]) + (ws_cd[2] + ws_cd[3]),
                             (ws_cb[0] + ws_cb[1]) + (ws_cb[2] + ws_cb[3]));
    }
    if (i < 16) {   // per-(c,pol) row seed flags
        int c = i >> 1, pol = i & 1;
        unsigned long long o = wmask[c][0] | wmask[c][1] | wmask[c][2] | wmask[c][3];
        unsigned long long a = wmask[c][0] & wmask[c][1] & wmask[c][2] & wmask[c][3];
        bool any = pol ? (a != ~0ull) : (o != 0ull);
        int j = ((b * C_DIM + c) << 1) + pol;
        rowflagP[(j << 8) + y] = any ? 1 : 0;
    }

    unsigned long long lm_le = (~0ull) >> (63 - lane);
    unsigned long long lm_ge = (~0ull) << lane;

#pragma unroll 1
    for (int c = 0; c < C_DIM; ++c) {
        unsigned long long m0 = wmask[c][wid];
        int d1v[2];
#pragma unroll
        for (int pol = 0; pol < 2; ++pol) {
            unsigned long long mk = pol ? ~m0 : m0;
            unsigned long long mle = mk & lm_le;
            unsigned long long mge = mk & lm_ge;
            int last, next;
            if (mle) last = (wid << 6) + 63 - __builtin_clzll(mle);
            else {
                last = -1000;
                for (int w = wid - 1; w >= 0; --w) {
                    unsigned long long mw = pol ? ~wmask[c][w] : wmask[c][w];
                    if (mw) { last = (w << 6) + 63 - __builtin_clzll(mw); break; }
                }
            }
            if (mge) next = (wid << 6) + __builtin_ctzll(mge);
            else {
                next = 100000;
                for (int w = wid + 1; w < 4; ++w) {
                    unsigned long long mw = pol ? ~wmask[c][w] : wmask[c][w];
                    if (mw) { next = (w << 6) + __builtin_ctzll(mw); break; }
                }
            }
            d1v[pol] = min(min(i - last, next - i), 512);
        }
        int bc = b * C_DIM + c;
        d1t[(((size_t)bc * 16 + (i >> 4)) * 256 + y) * 16 + (i & 15)] =
            (unsigned int)d1v[0] | ((unsigned int)d1v[1] << 16);
    }
}

// ------------- Kernel 2: windowed vertical envelope (wave-uniform trip count) + finalize ------
// grid 1024: blk -> bc = blk>>5, xt = (blk>>1)&15, yh = blk&1
// thread tile: 2 y-rows x 4 x-cols; ybase = yh*128 + (tid>>2)*2
#define LDS_PITCH 20
// One window step for polarity P (lo/hi half of packed word). Q: uint4, DY2A/DY2B: dy^2 for iy=0/1.
#define STEP_LO(Q, MA, MB, DY2A, DY2B)                                          \
    {                                                                           \
        float e0 = (float)(Q.x & 0xFFFFu), e1 = (float)(Q.y & 0xFFFFu);         \
        float e2 = (float)(Q.z & 0xFFFFu), e3 = (float)(Q.w & 0xFFFFu);         \
        MA.x = fminf(MA.x, fmaf(e0, e0, DY2A)); MB.x = fminf(MB.x, fmaf(e0, e0, DY2B)); \
        MA.y = fminf(MA.y, fmaf(e1, e1, DY2A)); MB.y = fminf(MB.y, fmaf(e1, e1, DY2B)); \
        MA.z = fminf(MA.z, fmaf(e2, e2, DY2A)); MB.z = fminf(MB.z, fmaf(e2, e2, DY2B)); \
        MA.w = fminf(MA.w, fmaf(e3, e3, DY2A)); MB.w = fminf(MB.w, fmaf(e3, e3, DY2B)); \
    }
#define STEP_HI(Q, MA, MB, DY2A, DY2B)                                          \
    {                                                                           \
        float e0 = (float)(Q.x >> 16), e1 = (float)(Q.y >> 16);                 \
        float e2 = (float)(Q.z >> 16), e3 = (float)(Q.w >> 16);                 \
        MA.x = fminf(MA.x, fmaf(e0, e0, DY2A)); MB.x = fminf(MB.x, fmaf(e0, e0, DY2B)); \
        MA.y = fminf(MA.y, fmaf(e1, e1, DY2A)); MB.y = fminf(MB.y, fmaf(e1, e1, DY2B)); \
        MA.z = fminf(MA.z, fmaf(e2, e2, DY2A)); MB.z = fminf(MB.z, fmaf(e2, e2, DY2B)); \
        MA.w = fminf(MA.w, fmaf(e3, e3, DY2A)); MB.w = fminf(MB.w, fmaf(e3, e3, DY2B)); \
    }

__global__ void __launch_bounds__(256) k_cols_fin(
    const unsigned int* __restrict__ d1t, const float* __restrict__ x,
    const float* __restrict__ lse, const int* __restrict__ tgt,
    const unsigned char* __restrict__ rowflagP,
    const float* __restrict__ pce, const float* __restrict__ pinter,
    const int2* __restrict__ pcnt, float* __restrict__ pbound,
    unsigned int* __restrict__ done, float* __restrict__ out) {
    int blk = blockIdx.x;            // [0, 1024)
    int bc = blk >> 5;               // [0, 32)
    int xt = (blk >> 1) & 15;
    int yh = blk & 1;
    int b = bc >> 3, c = bc & 7;
    int tid = threadIdx.x;
    int tx = tid & 3;
    int ybase = (yh << 7) + ((tid >> 2) << 1);   // 2-row tile
    int lane = tid & 63, wid = tid >> 6;

    __shared__ unsigned int hp[H_DIM][LDS_PITCH];   // packed d1 words
    __shared__ int anyf[2];
    __shared__ double dred[256];
    __shared__ float wsum[4];
    __shared__ int sh_last;

    if (tid < 2) anyf[tid] = 0;
    __syncthreads();
    {
        int j0 = bc << 1;
        unsigned char f0 = rowflagP[(j0 << 8) + tid];
        unsigned char f1 = rowflagP[((j0 + 1) << 8) + tid];
        unsigned long long b0 = __ballot(f0 != 0);
        unsigned long long b1 = __ballot(f1 != 0);
        if (lane == 0) {
            if (b0) atomicOr(&anyf[0], 1);
            if (b1) atomicOr(&anyf[1], 1);
        }
    }

    // stage the full packed column tile (16KB contiguous) into pitch-20 LDS
    {
        const unsigned int* base = d1t + ((size_t)bc * 16 + xt) * 4096;
#pragma unroll
        for (int k = 0; k < 4; ++k) {
            uint4 q = *(const uint4*)(base + (k << 10) + (tid << 2));
            int y = (tid >> 2) + (k << 6);
            *(uint4*)&hp[y][(tid & 3) << 2] = q;
        }
    }
    __syncthreads();

    // per-thread window radius from its 8 pixels (both pols): r = max d1 + 1  (exact bound)
    uint4 q0 = *(const uint4*)&hp[ybase][tx << 2];
    uint4 q1 = *(const uint4*)&hp[ybase + 1][tx << 2];
    int dmax;
    {
        unsigned int w0 = max(max(q0.x, q0.y), max(q0.z, q0.w));
        unsigned int w1 = max(max(q1.x, q1.y), max(q1.z, q1.w));
        // max of both halves across the 8 words
        unsigned int lo = max(max(q0.x & 0xFFFFu, q0.y & 0xFFFFu), max(q0.z & 0xFFFFu, q0.w & 0xFFFFu));
        lo = max(lo, max(max(q1.x & 0xFFFFu, q1.y & 0xFFFFu), max(q1.z & 0xFFFFu, q1.w & 0xFFFFu)));
        unsigned int hi = max(w0 >> 16, w1 >> 16);
        dmax = (int)max(lo, hi);
    }
    int R = wave_reduce_max_i(dmax) + 1;
    R = __builtin_amdgcn_readfirstlane(min(R, H_DIM));
    int nIter = 2 * R + 2;                       // window rows: ybase-R .. ybase+1+R

    float4 m0a, m0b, m1a, m1b;
    m0a.x = m0a.y = m0a.z = m0a.w = 1e30f; m0b = m0a; m1a = m0a; m1b = m0a;

    // unified uniform loop over both pols, unrolled x2
    for (int kk = 0; kk < nIter; kk += 2) {
        int ypA = min(max(ybase - R + kk, 0), H_DIM - 1);
        int ypB = min(max(ybase - R + kk + 1, 0), H_DIM - 1);
        uint4 qa = *(const uint4*)&hp[ypA][tx << 2];
        uint4 qb = *(const uint4*)&hp[ypB][tx << 2];
        float dA = (float)(ybase - ypA), dB = (float)(ybase - ypB);
        float dA2a = dA * dA, dA2b = (dA + 1.0f) * (dA + 1.0f);
        float dB2a = dB * dB, dB2b = (dB + 1.0f) * (dB + 1.0f);
        STEP_LO(qa, m0a, m0b, dA2a, dA2b)
        STEP_HI(qa, m1a, m1b, dA2a, dA2b)
        STEP_LO(qb, m0a, m0b, dB2a, dB2b)
        STEP_HI(qb, m1a, m1b, dB2a, dB2b)
    }

    bool has_pos = anyf[0] != 0;
    bool has_neg = anyf[1] != 0;

    float lsum = 0.f;
    size_t pixbase = (size_t)b * HW;
    size_t xbase = ((size_t)b * C_DIM + c) * HW;
    int x0 = (xt << 4) + (tx << 2);
#pragma unroll
    for (int iy = 0; iy < 2; ++iy) {
        int y = ybase + iy;
        size_t rowoff = (size_t)y * W_DIM + x0;
        float4 xv = *(const float4*)(x + xbase + rowoff);
        float4 lv = *(const float4*)(lse + pixbase + rowoff);
        int4 tv = *(const int4*)(tgt + pixbase + rowoff);
        float4 M0 = iy ? m0b : m0a;
        float4 M1 = iy ? m1b : m1a;
#pragma unroll
        for (int j = 0; j < 4; ++j) {
            float d2o = (j == 0) ? M0.x : (j == 1) ? M0.y : (j == 2) ? M0.z : M0.w;
            float d2i = (j == 0) ? M1.x : (j == 1) ? M1.y : (j == 2) ? M1.z : M1.w;
            float dout = sqrtf(d2o), din = sqrtf(d2i);
            float sgn = has_pos ? (has_neg ? (dout - din) : dout) : 0.f;
            float xs = (j == 0) ? xv.x : (j == 1) ? xv.y : (j == 2) ? xv.z : xv.w;
            float ls = (j == 0) ? lv.x : (j == 1) ? lv.y : (j == 2) ? lv.z : lv.w;
            int tt   = (j == 0) ? tv.x : (j == 1) ? tv.y : (j == 2) ? tv.z : tv.w;
            bool vb = (tt >= 0) && (tt < C_DIM);
            float prob = __expf(xs - ls);
            lsum += vb ? prob * sgn : 0.f;
        }
    }

    float r2 = wave_reduce_f(lsum);
    if (lane == 0) wsum[wid] = r2;
    __syncthreads();
    if (tid == 0) {
        pbound[blk] = (wsum[0] + wsum[1]) + (wsum[2] + wsum[3]);
        __threadfence();
        unsigned int o = atomicAdd(done, 1u);
        sh_last = (o == 1023u) ? 1 : 0;
    }
    __syncthreads();
    if (!sh_last) return;

    // ---- last block: final combine ----
    __threadfence();
    double s_ce = 0, s_in = 0, s_bd = 0, c_d = 0, c_b = 0;
    for (int k = tid; k < 1024; k += 256) {
        s_ce += (double)pce[k]; s_in += (double)pinter[k];
        int2 cc = pcnt[k]; c_d += (double)cc.x; c_b += (double)cc.y;
        s_bd += (double)pbound[k];
    }

    double sums[4]; double vin[4] = {s_ce, s_in, s_bd, c_d * 4194304.0 + c_b};
    for (int q = 0; q < 4; ++q) {
        dred[tid] = vin[q];
        __syncthreads();
        for (int s2 = 128; s2; s2 >>= 1) { if (tid < s2) dred[tid] += dred[tid + s2]; __syncthreads(); }
        sums[q] = dred[0];
        __syncthreads();
    }
    if (tid == 0) {
        double packed = sums[3];
        double cd = floor(packed / 4194304.0 + 1e-9);
        double cb = packed - cd * 4194304.0;
        double ce = sums[0] / (double)NPIX;
        double inter = sums[1];
        double card = cd + cb;
        double dice = 1.0 - (2.0 * inter + 1e-6) / (card + 1e-6);
        double dice_total = 0.1 * ce + 0.9 * dice;
        double bound = sums[2] / (cb + 1e-8);
        out[0] = (float)(0.1 * ce + 0.8 * dice_total + 0.1 * bound);
    }
}

extern "C" void kernel_launch(void* const* d_in, const int* in_sizes, int n_in,
                              void* d_out, int out_size, void* d_ws, size_t ws_size,
                              hipStream_t stream) {
    const float* x = (const float*)d_in[0];
    const int* tgt = (const int*)d_in[1];
    float* out = (float*)d_out;

    char* ws = (char*)d_ws;
    float* pce    = (float*)(ws + 0);
    float* pinter = (float*)(ws + 4096);
    int2*  pcnt   = (int2*)(ws + 8192);
    float* pbound = (float*)(ws + 16384);
    unsigned int* done = (unsigned int*)(ws + 20480);
    unsigned char* rowflagP = (unsigned char*)(ws + 24576);
    float* lse    = (float*)(ws + 65536);
    unsigned int* d1t = (unsigned int*)(ws + (size_t)(2u << 20));

    k_row<<<1024, 256, 0, stream>>>(x, tgt, lse, pce, pinter, pcnt, rowflagP, d1t, done);
    k_cols_fin<<<1024, 256, 0, stream>>>(d1t, x, lse, tgt, rowflagP,
                                         pce, pinter, pcnt, pbound, done, out);
}